// Round 1
// 2256.004 us; speedup vs baseline: 1.3287x; 1.3287x over previous
//
#include <hip/hip_runtime.h>

#define NN 50000
#define NE 800000

typedef __attribute__((ext_vector_type(8))) short short8;
typedef __attribute__((ext_vector_type(4))) short short4v;
typedef __attribute__((ext_vector_type(4))) float floatx4;

// ---- bf16 split helpers: x ~= hi(trunc) + lo(RNE) , error ~2^-17 |x| ----
__device__ inline unsigned short bf16_hi_trunc(float x) {
    return (unsigned short)(__builtin_bit_cast(unsigned, x) >> 16);
}
__device__ inline unsigned short bf16_lo_rne(float x) {
    unsigned hu = __builtin_bit_cast(unsigned, x) & 0xFFFF0000u;
    float rest = x - __builtin_bit_cast(float, hu);
    unsigned r = __builtin_bit_cast(unsigned, rest);
    r += 0x7FFFu + ((r >> 16) & 1u);
    return (unsigned short)(r >> 16);
}

// ---------------- degree histogram, all 4 graphs ----------------
__global__ void count_all_kernel(const int* __restrict__ c0, const int* __restrict__ c1,
                                 const int* __restrict__ c2, const int* __restrict__ c3,
                                 int* __restrict__ cnt, int E, int N) {
    int e = blockIdx.x * blockDim.x + threadIdx.x;
    if (e >= E) return;
    int g = blockIdx.y;
    const int* col = (g == 0) ? c0 : (g == 1) ? c1 : (g == 2) ? c2 : c3;
    atomicAdd(&cnt[(size_t)g * N + col[e]], 1);
}

// ---------------- exclusive scan (one block per graph) + dinv ----------------
__global__ __launch_bounds__(1024) void scan_dinv_kernel(const int* __restrict__ cnt_all,
                                                         int* __restrict__ offs_all,
                                                         float* __restrict__ dinv_all, int N) {
    __shared__ int sums[1024];
    const int T = 1024;
    int g = blockIdx.x;
    const int* cnt = cnt_all + (size_t)g * N;
    int* offs = offs_all + (size_t)g * (N + 1);
    float* dinv = dinv_all + (size_t)g * N;

    int tid = threadIdx.x;
    int chunk = (N + T - 1) / T;
    int start = tid * chunk;
    int end = start + chunk; if (end > N) end = N;
    int s = 0;
    for (int i = start; i < end; ++i) s += cnt[i];
    sums[tid] = s;
    __syncthreads();
    for (int off = 1; off < T; off <<= 1) {
        int v = (tid >= off) ? sums[tid - off] : 0;
        __syncthreads();
        sums[tid] += v;
        __syncthreads();
    }
    int run = sums[tid] - s;  // exclusive prefix
    for (int i = start; i < end; ++i) {
        offs[i] = run;
        int c = cnt[i];
        run += c;
        dinv[i] = rsqrtf((float)(c + 1));  // +1 self-loop; always > 0
    }
    if (tid == T - 1) offs[N] = sums[T - 1];
}

// ---------------- CSR fill (by target node), all 4 graphs ----------------
__global__ void fill_all_kernel(const int* __restrict__ ei0, const int* __restrict__ ei1,
                                const int* __restrict__ ei2, const int* __restrict__ ei3,
                                const int* __restrict__ offs, int* __restrict__ cursor,
                                const float* __restrict__ dinv,
                                int* __restrict__ csr_src, float* __restrict__ csr_norm,
                                int E, int N) {
    int e = blockIdx.x * blockDim.x + threadIdx.x;
    if (e >= E) return;
    int g = blockIdx.y;
    const int* ei = (g == 0) ? ei0 : (g == 1) ? ei1 : (g == 2) ? ei2 : ei3;
    int r = ei[e], c = ei[E + e];
    int p = atomicAdd(&cursor[(size_t)g * N + c], 1);
    int idx = offs[(size_t)g * (N + 1) + c] + p;
    csr_src[(size_t)g * E + idx] = r;
    csr_norm[(size_t)g * E + idx] = dinv[(size_t)g * N + r] * dinv[(size_t)g * N + c];
}

// ---------------- weight pack: W[g][k][n] fp32 -> Wt[g][n][k] bf16 hi/lo ----------------
__global__ __launch_bounds__(256) void pack_w_kernel(const float* __restrict__ Wc,
                                                     const float* __restrict__ Wm,
                                                     const float* __restrict__ Wl,
                                                     short* __restrict__ WcT_hi,
                                                     short* __restrict__ WcT_lo,
                                                     short* __restrict__ WmlT_hi,
                                                     short* __restrict__ WmlT_lo) {
    int idx = blockIdx.x * 256 + threadIdx.x;  // over 4*256*256
    int g = idx >> 16;
    int n = (idx >> 8) & 255;
    int k = idx & 255;
    float wc = Wc[((size_t)(g * 256 + k) * 256) + n];
    WcT_hi[idx] = (short)bf16_hi_trunc(wc);
    WcT_lo[idx] = (short)bf16_lo_rne(wc);
    float wml = (n < 128) ? Wm[((size_t)(g * 256 + k) * 128) + n]
                          : Wl[((size_t)(g * 256 + k) * 128) + (n - 128)];
    WmlT_hi[idx] = (short)bf16_hi_trunc(wml);
    WmlT_lo[idx] = (short)bf16_lo_rne(wml);
}

// ---------------- split-bf16 MFMA GEMM: C[M,Nc] = A[M,256] @ B[256,Nc] ----------------
__global__ __launch_bounds__(256) void gemm_mfma_kernel(const float* __restrict__ A,
                                                        const short* __restrict__ Bt_hi,
                                                        const short* __restrict__ Bt_lo,
                                                        float* __restrict__ C, int M, int Nc) {
    __shared__ __align__(16) short As_hi[128][40];  // [m][k] k-chunk=32, pad->40
    __shared__ __align__(16) short As_lo[128][40];

    int t = threadIdx.x;
    int lane = t & 63;
    int wave = t >> 6;
    int wm = (wave & 1) * 64;
    int wn = (wave >> 1) * 64;
    int row_blk = blockIdx.y * 128;
    int col_blk = blockIdx.x * 128;

    int kq = (t & 7) * 4;
    int rb = t >> 3;  // 0..31

    int al = lane & 15;
    int ak = (lane >> 4) * 8;

    floatx4 acc[4][4] = {};

    for (int k0 = 0; k0 < 256; k0 += 32) {
        __syncthreads();
#pragma unroll
        for (int p = 0; p < 4; ++p) {
            int r = rb + p * 32;
            int gr = row_blk + r;
            float4 v = make_float4(0.f, 0.f, 0.f, 0.f);
            if (gr < M) v = *(const float4*)(A + (size_t)gr * 256 + k0 + kq);
            short4v h4, l4;
            h4[0] = (short)bf16_hi_trunc(v.x); l4[0] = (short)bf16_lo_rne(v.x);
            h4[1] = (short)bf16_hi_trunc(v.y); l4[1] = (short)bf16_lo_rne(v.y);
            h4[2] = (short)bf16_hi_trunc(v.z); l4[2] = (short)bf16_lo_rne(v.z);
            h4[3] = (short)bf16_hi_trunc(v.w); l4[3] = (short)bf16_lo_rne(v.w);
            *(short4v*)&As_hi[r][kq] = h4;
            *(short4v*)&As_lo[r][kq] = l4;
        }
        __syncthreads();

        short8 bh[4], bl4[4];
#pragma unroll
        for (int nt = 0; nt < 4; ++nt) {
            const short* ph = Bt_hi + (size_t)(col_blk + wn + nt * 16 + al) * 256 + k0 + ak;
            const short* pl = Bt_lo + (size_t)(col_blk + wn + nt * 16 + al) * 256 + k0 + ak;
            bh[nt] = *(const short8*)ph;
            bl4[nt] = *(const short8*)pl;
        }

#pragma unroll
        for (int mt = 0; mt < 4; ++mt) {
            short8 ah = *(const short8*)&As_hi[wm + mt * 16 + al][ak];
            short8 alo = *(const short8*)&As_lo[wm + mt * 16 + al][ak];
#pragma unroll
            for (int nt = 0; nt < 4; ++nt) {
                acc[mt][nt] = __builtin_amdgcn_mfma_f32_16x16x32_bf16(ah, bh[nt], acc[mt][nt], 0, 0, 0);
                acc[mt][nt] = __builtin_amdgcn_mfma_f32_16x16x32_bf16(ah, bl4[nt], acc[mt][nt], 0, 0, 0);
                acc[mt][nt] = __builtin_amdgcn_mfma_f32_16x16x32_bf16(alo, bh[nt], acc[mt][nt], 0, 0, 0);
            }
        }
    }

    int rq = lane >> 4;
#pragma unroll
    for (int mt = 0; mt < 4; ++mt) {
        int rbase = row_blk + wm + mt * 16 + rq * 4;
#pragma unroll
        for (int reg = 0; reg < 4; ++reg) {
            int r = rbase + reg;
            if (r < M) {
#pragma unroll
                for (int nt = 0; nt < 4; ++nt) {
                    C[(size_t)r * Nc + col_blk + wn + nt * 16 + al] = acc[mt][nt][reg];
                }
            }
        }
    }
}

// ---------------- aggregation v2: one wave per node, float4 lanes, 4-edge MLP ----------------
__global__ __launch_bounds__(256) void agg_kernel(const float* __restrict__ Hlin,
                                                  const float* __restrict__ dinv,
                                                  const int* __restrict__ offs,
                                                  const int* __restrict__ csr_src,
                                                  const float* __restrict__ csr_norm,
                                                  const float* __restrict__ bias,
                                                  float* __restrict__ Hout) {
    int node = __builtin_amdgcn_readfirstlane(blockIdx.x * 4 + (threadIdx.x >> 6));
    if (node >= NN) return;
    int lane = threadIdx.x & 63;

    float di = dinv[node];
    float dd = di * di;
    floatx4 acc = *(const floatx4*)(bias + 4 * lane);
    floatx4 self = *(const floatx4*)(Hlin + (size_t)node * 256 + 4 * lane);
    acc += dd * self;

    int s = __builtin_amdgcn_readfirstlane(offs[node]);
    int e = __builtin_amdgcn_readfirstlane(offs[node + 1]);
    int j = s;
    for (; j + 4 <= e; j += 4) {
        int s0 = csr_src[j + 0], s1 = csr_src[j + 1], s2 = csr_src[j + 2], s3 = csr_src[j + 3];
        float n0 = csr_norm[j + 0], n1 = csr_norm[j + 1], n2 = csr_norm[j + 2], n3 = csr_norm[j + 3];
        floatx4 v0 = *(const floatx4*)(Hlin + (size_t)s0 * 256 + 4 * lane);
        floatx4 v1 = *(const floatx4*)(Hlin + (size_t)s1 * 256 + 4 * lane);
        floatx4 v2 = *(const floatx4*)(Hlin + (size_t)s2 * 256 + 4 * lane);
        floatx4 v3 = *(const floatx4*)(Hlin + (size_t)s3 * 256 + 4 * lane);
        acc += n0 * v0;
        acc += n1 * v1;
        acc += n2 * v2;
        acc += n3 * v3;
    }
    for (; j < e; ++j) {
        int s0 = csr_src[j];
        float n0 = csr_norm[j];
        acc += n0 * *(const floatx4*)(Hlin + (size_t)s0 * 256 + 4 * lane);
    }
    *(floatx4*)(Hout + (size_t)node * 256 + 4 * lane) = acc;
}

// ---------------- dual aggregation v2 on fused [mu|ls] layout [N,256] ----------------
__global__ __launch_bounds__(256) void agg_dual_kernel(const float* __restrict__ Lin,
                                                       const float* __restrict__ dinv,
                                                       const int* __restrict__ offs,
                                                       const int* __restrict__ csr_src,
                                                       const float* __restrict__ csr_norm,
                                                       const float* __restrict__ bm,
                                                       const float* __restrict__ bl,
                                                       float* __restrict__ out_mu,
                                                       float* __restrict__ out_ls) {
    int node = __builtin_amdgcn_readfirstlane(blockIdx.x * 4 + (threadIdx.x >> 6));
    if (node >= NN) return;
    int lane = threadIdx.x & 63;

    float di = dinv[node];
    float dd = di * di;
    const float* bp = (lane < 32) ? (bm + 4 * lane) : (bl + 4 * (lane - 32));
    floatx4 acc = *(const floatx4*)bp;
    floatx4 self = *(const floatx4*)(Lin + (size_t)node * 256 + 4 * lane);
    acc += dd * self;

    int s = __builtin_amdgcn_readfirstlane(offs[node]);
    int e = __builtin_amdgcn_readfirstlane(offs[node + 1]);
    int j = s;
    for (; j + 4 <= e; j += 4) {
        int s0 = csr_src[j + 0], s1 = csr_src[j + 1], s2 = csr_src[j + 2], s3 = csr_src[j + 3];
        float n0 = csr_norm[j + 0], n1 = csr_norm[j + 1], n2 = csr_norm[j + 2], n3 = csr_norm[j + 3];
        floatx4 v0 = *(const floatx4*)(Lin + (size_t)s0 * 256 + 4 * lane);
        floatx4 v1 = *(const floatx4*)(Lin + (size_t)s1 * 256 + 4 * lane);
        floatx4 v2 = *(const floatx4*)(Lin + (size_t)s2 * 256 + 4 * lane);
        floatx4 v3 = *(const floatx4*)(Lin + (size_t)s3 * 256 + 4 * lane);
        acc += n0 * v0;
        acc += n1 * v1;
        acc += n2 * v2;
        acc += n3 * v3;
    }
    for (; j < e; ++j) {
        int s0 = csr_src[j];
        float n0 = csr_norm[j];
        acc += n0 * *(const floatx4*)(Lin + (size_t)s0 * 256 + 4 * lane);
    }
    float* op = (lane < 32) ? (out_mu + (size_t)node * 128 + 4 * lane)
                            : (out_ls + (size_t)node * 128 + 4 * (lane - 32));
    *(floatx4*)op = acc;
}

extern "C" void kernel_launch(void* const* d_in, const int* in_sizes, int n_in,
                              void* d_out, int out_size, void* d_ws, size_t ws_size,
                              hipStream_t stream) {
    const int N = NN, E = NE;
    const float* Wc = (const float*)d_in[8];
    const float* bc = (const float*)d_in[9];
    const float* Wm = (const float*)d_in[10];
    const float* bm = (const float*)d_in[11];
    const float* Wl = (const float*)d_in[12];
    const float* bl = (const float*)d_in[13];
    float* out = (float*)d_out;

    // workspace layout (~134 MB)
    float* buf_lin  = (float*)d_ws;                         // N*256
    float* buf_h    = buf_lin + (size_t)N * 256;            // N*256
    float* dinv     = buf_h + (size_t)N * 256;              // 4N
    int*   cnt      = (int*)(dinv + 4 * (size_t)N);         // 4N
    int*   offs     = cnt + 4 * (size_t)N;                  // 4*(N+1)
    int*   cursor   = offs + 4 * ((size_t)N + 1);           // 4N
    int*   csr_src  = cursor + 4 * (size_t)N;               // 4E
    float* csr_norm = (float*)(csr_src + 4 * (size_t)E);    // 4E
    short* WcT_hi   = (short*)(csr_norm + 4 * (size_t)E);   // 4*65536 each
    short* WcT_lo   = WcT_hi + 4 * 65536;
    short* WmlT_hi  = WcT_lo + 4 * 65536;
    short* WmlT_lo  = WmlT_hi + 4 * 65536;

    const int* ei0 = (const int*)d_in[1];
    const int* ei1 = (const int*)d_in[3];
    const int* ei2 = (const int*)d_in[5];
    const int* ei3 = (const int*)d_in[7];

    // weights + CSR prep for all 4 graphs, batched
    pack_w_kernel<<<1024, 256, 0, stream>>>(Wc, Wm, Wl, WcT_hi, WcT_lo, WmlT_hi, WmlT_lo);
    hipMemsetAsync(cnt, 0, 4 * (size_t)N * sizeof(int), stream);
    hipMemsetAsync(cursor, 0, 4 * (size_t)N * sizeof(int), stream);
    count_all_kernel<<<dim3((E + 255) / 256, 4), 256, 0, stream>>>(
        ei0 + E, ei1 + E, ei2 + E, ei3 + E, cnt, E, N);
    scan_dinv_kernel<<<4, 1024, 0, stream>>>(cnt, offs, dinv, N);
    fill_all_kernel<<<dim3((E + 255) / 256, 4), 256, 0, stream>>>(
        ei0, ei1, ei2, ei3, offs, cursor, dinv, csr_src, csr_norm, E, N);

    for (int g = 0; g < 4; ++g) {
        const float* x = (const float*)d_in[2 * g];
        const float* dv = dinv + (size_t)g * N;
        const int* of = offs + (size_t)g * (N + 1);
        const int* cs = csr_src + (size_t)g * E;
        const float* cn = csr_norm + (size_t)g * E;

        // conv1 linear: buf_lin = x @ Wc   [N,256]
        gemm_mfma_kernel<<<dim3(2, (N + 127) / 128), 256, 0, stream>>>(
            x, WcT_hi + (size_t)g * 65536, WcT_lo + (size_t)g * 65536, buf_lin, N, 256);
        // conv1 aggregate: buf_h = A_norm @ buf_lin + bc
        agg_kernel<<<(N + 3) / 4, 256, 0, stream>>>(buf_lin, dv, of, cs, cn,
                                                    bc + (size_t)g * 256, buf_h);
        // conv2+conv3 linear fused: buf_lin = buf_h @ [Wm|Wl]   [N,256]
        gemm_mfma_kernel<<<dim3(2, (N + 127) / 128), 256, 0, stream>>>(
            buf_h, WmlT_hi + (size_t)g * 65536, WmlT_lo + (size_t)g * 65536, buf_lin, N, 256);
        // dual aggregate
        agg_dual_kernel<<<(N + 3) / 4, 256, 0, stream>>>(buf_lin, dv, of, cs, cn,
                                                         bm + (size_t)g * 128, bl + (size_t)g * 128,
                                                         out + (size_t)g * N * 128,
                                                         out + (size_t)(4 + g) * N * 128);
    }
}

// Round 3
// 1950.686 us; speedup vs baseline: 1.5366x; 1.1565x over previous
//
#include <hip/hip_runtime.h>

#define NN 50000
#define NE 800000

typedef __attribute__((ext_vector_type(8))) short short8;
typedef __attribute__((ext_vector_type(4))) short short4v;
typedef __attribute__((ext_vector_type(4))) unsigned short ushort4v;
typedef __attribute__((ext_vector_type(4))) float floatx4;

// ---- bf16 helpers ----
__device__ inline unsigned short bf16_hi_trunc(float x) {
    return (unsigned short)(__builtin_bit_cast(unsigned, x) >> 16);
}
__device__ inline unsigned short bf16_lo_rne(float x) {
    unsigned hu = __builtin_bit_cast(unsigned, x) & 0xFFFF0000u;
    float rest = x - __builtin_bit_cast(float, hu);
    unsigned r = __builtin_bit_cast(unsigned, rest);
    r += 0x7FFFu + ((r >> 16) & 1u);
    return (unsigned short)(r >> 16);
}
__device__ inline unsigned short bf16_rne(float x) {
    unsigned r = __builtin_bit_cast(unsigned, x);
    r += 0x7FFFu + ((r >> 16) & 1u);
    return (unsigned short)(r >> 16);
}
__device__ inline float bfu_to_f(unsigned short u) {
    return __builtin_bit_cast(float, ((unsigned)u) << 16);
}
__device__ inline floatx4 bf4_to_f4(ushort4v v) {
    floatx4 r;
    r[0] = bfu_to_f(v[0]); r[1] = bfu_to_f(v[1]);
    r[2] = bfu_to_f(v[2]); r[3] = bfu_to_f(v[3]);
    return r;
}

// ---------------- degree histogram, all 4 graphs ----------------
__global__ void count_all_kernel(const int* __restrict__ c0, const int* __restrict__ c1,
                                 const int* __restrict__ c2, const int* __restrict__ c3,
                                 int* __restrict__ cnt, int E, int N) {
    int e = blockIdx.x * blockDim.x + threadIdx.x;
    if (e >= E) return;
    int g = blockIdx.y;
    const int* col = (g == 0) ? c0 : (g == 1) ? c1 : (g == 2) ? c2 : c3;
    atomicAdd(&cnt[(size_t)g * N + col[e]], 1);
}

// ---------------- exclusive scan (one block per graph) + dinv ----------------
__global__ __launch_bounds__(1024) void scan_dinv_kernel(const int* __restrict__ cnt_all,
                                                         int* __restrict__ offs_all,
                                                         float* __restrict__ dinv_all, int N) {
    __shared__ int sums[1024];
    const int T = 1024;
    int g = blockIdx.x;
    const int* cnt = cnt_all + (size_t)g * N;
    int* offs = offs_all + (size_t)g * (N + 1);
    float* dinv = dinv_all + (size_t)g * N;

    int tid = threadIdx.x;
    int chunk = (N + T - 1) / T;
    int start = tid * chunk;
    int end = start + chunk; if (end > N) end = N;
    int s = 0;
    for (int i = start; i < end; ++i) s += cnt[i];
    sums[tid] = s;
    __syncthreads();
    for (int off = 1; off < T; off <<= 1) {
        int v = (tid >= off) ? sums[tid - off] : 0;
        __syncthreads();
        sums[tid] += v;
        __syncthreads();
    }
    int run = sums[tid] - s;  // exclusive prefix
    for (int i = start; i < end; ++i) {
        offs[i] = run;
        int c = cnt[i];
        run += c;
        dinv[i] = rsqrtf((float)(c + 1));  // +1 self-loop; always > 0
    }
    if (tid == T - 1) offs[N] = sums[T - 1];
}

// ---------------- CSR fill (by target), combined 8B records, all 4 graphs ----------------
__global__ void fill_all_kernel(const int* __restrict__ ei0, const int* __restrict__ ei1,
                                const int* __restrict__ ei2, const int* __restrict__ ei3,
                                const int* __restrict__ offs, int* __restrict__ cursor,
                                const float* __restrict__ dinv,
                                int2* __restrict__ rec, int E, int N) {
    int e = blockIdx.x * blockDim.x + threadIdx.x;
    if (e >= E) return;
    int g = blockIdx.y;
    const int* ei = (g == 0) ? ei0 : (g == 1) ? ei1 : (g == 2) ? ei2 : ei3;
    int r = ei[e], c = ei[E + e];
    int p = atomicAdd(&cursor[(size_t)g * N + c], 1);
    int idx = offs[(size_t)g * (N + 1) + c] + p;
    int2 v;
    v.x = r;
    v.y = __builtin_bit_cast(int, dinv[(size_t)g * N + r] * dinv[(size_t)g * N + c]);
    rec[(size_t)g * E + idx] = v;  // single 8B scattered store
}

// ---------------- weight pack: W[g][k][n] fp32 -> Wt[g][n][k] bf16 hi/lo ----------------
__global__ __launch_bounds__(256) void pack_w_kernel(const float* __restrict__ Wc,
                                                     const float* __restrict__ Wm,
                                                     const float* __restrict__ Wl,
                                                     short* __restrict__ WcT_hi,
                                                     short* __restrict__ WcT_lo,
                                                     short* __restrict__ WmlT_hi,
                                                     short* __restrict__ WmlT_lo) {
    int idx = blockIdx.x * 256 + threadIdx.x;  // over 4*256*256
    int g = idx >> 16;
    int n = (idx >> 8) & 255;
    int k = idx & 255;
    float wc = Wc[((size_t)(g * 256 + k) * 256) + n];
    WcT_hi[idx] = (short)bf16_hi_trunc(wc);
    WcT_lo[idx] = (short)bf16_lo_rne(wc);
    float wml = (n < 128) ? Wm[((size_t)(g * 256 + k) * 128) + n]
                          : Wl[((size_t)(g * 256 + k) * 128) + (n - 128)];
    WmlT_hi[idx] = (short)bf16_hi_trunc(wml);
    WmlT_lo[idx] = (short)bf16_lo_rne(wml);
}

// ---------------- split-bf16 MFMA GEMM: C[M,Nc] = A[M,256] @ B[256,Nc] ----------------
// BF16_OUT: write C as bf16(RNE) instead of fp32 (conv1 intermediate only).
template <bool BF16_OUT>
__global__ __launch_bounds__(256) void gemm_mfma_kernel(const float* __restrict__ A,
                                                        const short* __restrict__ Bt_hi,
                                                        const short* __restrict__ Bt_lo,
                                                        void* __restrict__ Cout, int M, int Nc) {
    __shared__ __align__(16) short As_hi[128][40];  // [m][k] k-chunk=32, pad->40
    __shared__ __align__(16) short As_lo[128][40];

    int t = threadIdx.x;
    int lane = t & 63;
    int wave = t >> 6;
    int wm = (wave & 1) * 64;
    int wn = (wave >> 1) * 64;
    int row_blk = blockIdx.y * 128;
    int col_blk = blockIdx.x * 128;

    int kq = (t & 7) * 4;
    int rb = t >> 3;  // 0..31

    int al = lane & 15;
    int ak = (lane >> 4) * 8;

    floatx4 acc[4][4] = {};

    for (int k0 = 0; k0 < 256; k0 += 32) {
        __syncthreads();
#pragma unroll
        for (int p = 0; p < 4; ++p) {
            int r = rb + p * 32;
            int gr = row_blk + r;
            float4 v = make_float4(0.f, 0.f, 0.f, 0.f);
            if (gr < M) v = *(const float4*)(A + (size_t)gr * 256 + k0 + kq);
            short4v h4, l4;
            h4[0] = (short)bf16_hi_trunc(v.x); l4[0] = (short)bf16_lo_rne(v.x);
            h4[1] = (short)bf16_hi_trunc(v.y); l4[1] = (short)bf16_lo_rne(v.y);
            h4[2] = (short)bf16_hi_trunc(v.z); l4[2] = (short)bf16_lo_rne(v.z);
            h4[3] = (short)bf16_hi_trunc(v.w); l4[3] = (short)bf16_lo_rne(v.w);
            *(short4v*)&As_hi[r][kq] = h4;
            *(short4v*)&As_lo[r][kq] = l4;
        }
        __syncthreads();

        short8 bh[4], bl4[4];
#pragma unroll
        for (int nt = 0; nt < 4; ++nt) {
            const short* ph = Bt_hi + (size_t)(col_blk + wn + nt * 16 + al) * 256 + k0 + ak;
            const short* pl = Bt_lo + (size_t)(col_blk + wn + nt * 16 + al) * 256 + k0 + ak;
            bh[nt] = *(const short8*)ph;
            bl4[nt] = *(const short8*)pl;
        }

#pragma unroll
        for (int mt = 0; mt < 4; ++mt) {
            short8 ah = *(const short8*)&As_hi[wm + mt * 16 + al][ak];
            short8 alo = *(const short8*)&As_lo[wm + mt * 16 + al][ak];
#pragma unroll
            for (int nt = 0; nt < 4; ++nt) {
                acc[mt][nt] = __builtin_amdgcn_mfma_f32_16x16x32_bf16(ah, bh[nt], acc[mt][nt], 0, 0, 0);
                acc[mt][nt] = __builtin_amdgcn_mfma_f32_16x16x32_bf16(ah, bl4[nt], acc[mt][nt], 0, 0, 0);
                acc[mt][nt] = __builtin_amdgcn_mfma_f32_16x16x32_bf16(alo, bh[nt], acc[mt][nt], 0, 0, 0);
            }
        }
    }

    int rq = lane >> 4;
#pragma unroll
    for (int mt = 0; mt < 4; ++mt) {
        int rbase = row_blk + wm + mt * 16 + rq * 4;
#pragma unroll
        for (int reg = 0; reg < 4; ++reg) {
            int r = rbase + reg;
            if (r < M) {
#pragma unroll
                for (int nt = 0; nt < 4; ++nt) {
                    size_t ci = (size_t)r * Nc + col_blk + wn + nt * 16 + al;
                    if constexpr (BF16_OUT) {
                        ((unsigned short*)Cout)[ci] = bf16_rne(acc[mt][nt][reg]);
                    } else {
                        ((float*)Cout)[ci] = acc[mt][nt][reg];
                    }
                }
            }
        }
    }
}

// ---------------- agg v3 (conv1): bf16 row gather, one wave/node, 4-edge MLP ----------------
__global__ __launch_bounds__(256) void agg_bf16_kernel(const unsigned short* __restrict__ Hlin,
                                                       const float* __restrict__ dinv,
                                                       const int* __restrict__ offs,
                                                       const int2* __restrict__ rec,
                                                       const float* __restrict__ bias,
                                                       float* __restrict__ Hout) {
    int node = __builtin_amdgcn_readfirstlane(blockIdx.x * 4 + (threadIdx.x >> 6));
    if (node >= NN) return;
    int lane = threadIdx.x & 63;

    float di = dinv[node];
    float dd = di * di;
    floatx4 acc = *(const floatx4*)(bias + 4 * lane);
    floatx4 self = bf4_to_f4(*(const ushort4v*)(Hlin + (size_t)node * 256 + 4 * lane));
    acc += dd * self;

    int s = __builtin_amdgcn_readfirstlane(offs[node]);
    int e = __builtin_amdgcn_readfirstlane(offs[node + 1]);
    int j = s;
    for (; j + 4 <= e; j += 4) {
        int2 r0 = rec[j + 0], r1 = rec[j + 1], r2 = rec[j + 2], r3 = rec[j + 3];
        floatx4 v0 = bf4_to_f4(*(const ushort4v*)(Hlin + (size_t)r0.x * 256 + 4 * lane));
        floatx4 v1 = bf4_to_f4(*(const ushort4v*)(Hlin + (size_t)r1.x * 256 + 4 * lane));
        floatx4 v2 = bf4_to_f4(*(const ushort4v*)(Hlin + (size_t)r2.x * 256 + 4 * lane));
        floatx4 v3 = bf4_to_f4(*(const ushort4v*)(Hlin + (size_t)r3.x * 256 + 4 * lane));
        acc += __builtin_bit_cast(float, r0.y) * v0;
        acc += __builtin_bit_cast(float, r1.y) * v1;
        acc += __builtin_bit_cast(float, r2.y) * v2;
        acc += __builtin_bit_cast(float, r3.y) * v3;
    }
    for (; j < e; ++j) {
        int2 r0 = rec[j];
        floatx4 v0 = bf4_to_f4(*(const ushort4v*)(Hlin + (size_t)r0.x * 256 + 4 * lane));
        acc += __builtin_bit_cast(float, r0.y) * v0;
    }
    *(floatx4*)(Hout + (size_t)node * 256 + 4 * lane) = acc;
}

// ---------------- dual aggregation (final): fp32 in, [mu|ls] out ----------------
__global__ __launch_bounds__(256) void agg_dual_kernel(const float* __restrict__ Lin,
                                                       const float* __restrict__ dinv,
                                                       const int* __restrict__ offs,
                                                       const int2* __restrict__ rec,
                                                       const float* __restrict__ bm,
                                                       const float* __restrict__ bl,
                                                       float* __restrict__ out_mu,
                                                       float* __restrict__ out_ls) {
    int node = __builtin_amdgcn_readfirstlane(blockIdx.x * 4 + (threadIdx.x >> 6));
    if (node >= NN) return;
    int lane = threadIdx.x & 63;

    float di = dinv[node];
    float dd = di * di;
    const float* bp = (lane < 32) ? (bm + 4 * lane) : (bl + 4 * (lane - 32));
    floatx4 acc = *(const floatx4*)bp;
    floatx4 self = *(const floatx4*)(Lin + (size_t)node * 256 + 4 * lane);
    acc += dd * self;

    int s = __builtin_amdgcn_readfirstlane(offs[node]);
    int e = __builtin_amdgcn_readfirstlane(offs[node + 1]);
    int j = s;
    for (; j + 4 <= e; j += 4) {
        int2 r0 = rec[j + 0], r1 = rec[j + 1], r2 = rec[j + 2], r3 = rec[j + 3];
        floatx4 v0 = *(const floatx4*)(Lin + (size_t)r0.x * 256 + 4 * lane);
        floatx4 v1 = *(const floatx4*)(Lin + (size_t)r1.x * 256 + 4 * lane);
        floatx4 v2 = *(const floatx4*)(Lin + (size_t)r2.x * 256 + 4 * lane);
        floatx4 v3 = *(const floatx4*)(Lin + (size_t)r3.x * 256 + 4 * lane);
        acc += __builtin_bit_cast(float, r0.y) * v0;
        acc += __builtin_bit_cast(float, r1.y) * v1;
        acc += __builtin_bit_cast(float, r2.y) * v2;
        acc += __builtin_bit_cast(float, r3.y) * v3;
    }
    for (; j < e; ++j) {
        int2 r0 = rec[j];
        floatx4 v0 = *(const floatx4*)(Lin + (size_t)r0.x * 256 + 4 * lane);
        acc += __builtin_bit_cast(float, r0.y) * v0;
    }
    float* op = (lane < 32) ? (out_mu + (size_t)node * 128 + 4 * lane)
                            : (out_ls + (size_t)node * 128 + 4 * (lane - 32));
    *(floatx4*)op = acc;
}

extern "C" void kernel_launch(void* const* d_in, const int* in_sizes, int n_in,
                              void* d_out, int out_size, void* d_ws, size_t ws_size,
                              hipStream_t stream) {
    const int N = NN, E = NE;
    const float* Wc = (const float*)d_in[8];
    const float* bc = (const float*)d_in[9];
    const float* Wm = (const float*)d_in[10];
    const float* bm = (const float*)d_in[11];
    const float* Wl = (const float*)d_in[12];
    const float* bl = (const float*)d_in[13];
    float* out = (float*)d_out;

    // workspace layout (~133 MB)
    float* buf_lin  = (float*)d_ws;                         // N*256 fp32 (or bf16 half-used)
    float* buf_h    = buf_lin + (size_t)N * 256;            // N*256
    float* dinv     = buf_h + (size_t)N * 256;              // 4N
    int*   cnt      = (int*)(dinv + 4 * (size_t)N);         // 4N
    int*   offs     = cnt + 4 * (size_t)N;                  // 4*(N+1)
    int*   cursor   = offs + 4 * ((size_t)N + 1);           // 4N
    int2*  csr_rec  = (int2*)(cursor + 4 * (size_t)N);      // 4E * 8B
    short* WcT_hi   = (short*)(csr_rec + 4 * (size_t)E);    // 4*65536 each
    short* WcT_lo   = WcT_hi + 4 * 65536;
    short* WmlT_hi  = WcT_lo + 4 * 65536;
    short* WmlT_lo  = WmlT_hi + 4 * 65536;

    const int* ei0 = (const int*)d_in[1];
    const int* ei1 = (const int*)d_in[3];
    const int* ei2 = (const int*)d_in[5];
    const int* ei3 = (const int*)d_in[7];

    // weights + CSR prep for all 4 graphs, batched
    pack_w_kernel<<<1024, 256, 0, stream>>>(Wc, Wm, Wl, WcT_hi, WcT_lo, WmlT_hi, WmlT_lo);
    hipMemsetAsync(cnt, 0, 4 * (size_t)N * sizeof(int), stream);
    hipMemsetAsync(cursor, 0, 4 * (size_t)N * sizeof(int), stream);
    count_all_kernel<<<dim3((E + 255) / 256, 4), 256, 0, stream>>>(
        ei0 + E, ei1 + E, ei2 + E, ei3 + E, cnt, E, N);
    scan_dinv_kernel<<<4, 1024, 0, stream>>>(cnt, offs, dinv, N);
    fill_all_kernel<<<dim3((E + 255) / 256, 4), 256, 0, stream>>>(
        ei0, ei1, ei2, ei3, offs, cursor, dinv, csr_rec, E, N);

    for (int g = 0; g < 4; ++g) {
        const float* x = (const float*)d_in[2 * g];
        const float* dv = dinv + (size_t)g * N;
        const int* of = offs + (size_t)g * (N + 1);
        const int2* cr = csr_rec + (size_t)g * E;

        // conv1 linear: buf_lin(bf16) = x @ Wc   [N,256]
        gemm_mfma_kernel<true><<<dim3(2, (N + 127) / 128), 256, 0, stream>>>(
            x, WcT_hi + (size_t)g * 65536, WcT_lo + (size_t)g * 65536, buf_lin, N, 256);
        // conv1 aggregate: buf_h = A_norm @ buf_lin + bc   (bf16 gather -> fp32)
        agg_bf16_kernel<<<(N + 3) / 4, 256, 0, stream>>>(
            (const unsigned short*)buf_lin, dv, of, cr, bc + (size_t)g * 256, buf_h);
        // conv2+conv3 linear fused: buf_lin(fp32) = buf_h @ [Wm|Wl]   [N,256]
        gemm_mfma_kernel<false><<<dim3(2, (N + 127) / 128), 256, 0, stream>>>(
            buf_h, WmlT_hi + (size_t)g * 65536, WmlT_lo + (size_t)g * 65536, buf_lin, N, 256);
        // dual aggregate (fp32, final)
        agg_dual_kernel<<<(N + 3) / 4, 256, 0, stream>>>(
            buf_lin, dv, of, cr, bm + (size_t)g * 128, bl + (size_t)g * 128,
            out + (size_t)g * N * 128, out + (size_t)(4 + g) * N * 128);
    }
}